// Round 15
// baseline (758.882 us; speedup 1.0000x reference)
//
#include <hip/hip_runtime.h>

typedef unsigned short u16;
typedef unsigned int   u32;
typedef int      i32x4  __attribute__((ext_vector_type(4)));
typedef int      i32x8  __attribute__((ext_vector_type(8)));
typedef float    f32x4  __attribute__((ext_vector_type(4)));
typedef _Float16 f16x8  __attribute__((ext_vector_type(8)));

// Problem constants
#define LHW   53
#define NP    2809
#define KDIM  3072
#define NMEM  8192
#define PADW  84
#define IMG   64
#define MPAD  2816           // 22 * 128 zero-padded patch rows
#define BIGF  3.402823466e+38f
#define MARGIN 128.0f        // fp4-screen margin (~6 sigma incl. selection bias)
#define ROWB  1536           // bytes per fp4 row (3072 * 0.5)

// ---------------- fast-path ws layout (byte offsets, 256-aligned) ----------
#define O_XP    0UL           // 21168 f32
#define O_MSQ   84736UL       // 8192 f32
#define O_MQ4   117504UL      // 8192*1536 B fp4
#define O_AQ4   12700416UL    // 2816*1536 B fp4
#define O_D     17025792UL    // 2816*8192 f16 (D - 3072)
#define O_PVAL  63163136UL    // 2816*128 f32 block-mins
#define O_ROWI  64604928UL    // NP i32
#define O_ACC   64616192UL    // 12288 f32
#define WS_NEED6 64665344UL

// ---------------- legacy (fallback) ws layout (float-unit offsets) ---------
#define F_XP    0
#define F_MSQ   21504
#define F_PVAL  29696
#define F_PIDX  119584
#define F_ROW   209472
#define F_ACC   212288
#define F_MAX   224576
#define NSPL    32
#define NRANGE  (NMEM / NSPL)

// f32 -> OCP e2m1 nibble (s|e|e|m), RNE onto {0,.5,1,1.5,2,3,4,6}, clamp 6
__device__ inline u32 q4(float x) {
    float a = fminf(fabsf(x), 6.0f);
    u32 s = (__float_as_uint(x) >> 31) << 3;
    int v2;                                   // quantized value * 2
    if (a < 2.0f)      v2 = __float2int_rn(a * 2.0f);     // {0..4}
    else if (a < 4.0f) v2 = __float2int_rn(a) * 2;        // {4,6,8}
    else               v2 = __float2int_rn(a * 0.5f) * 4; // {8,12}
    u32 e;
    if (v2 <= 3)      e = (u32)v2;   // 0, 0.5, 1, 1.5
    else if (v2 == 4) e = 4u;        // 2
    else if (v2 == 6) e = 5u;        // 3
    else if (v2 == 8) e = 6u;        // 4
    else              e = 7u;        // 6
    return s | e;
}

// ============================ shared small kernels ==========================
// padded image; also zero-inits the output accumulator (atomic target)
__global__ void k_xp(const float* __restrict__ image, float* __restrict__ xp,
                     float* __restrict__ accb) {
    int id = blockIdx.x * 256 + threadIdx.x;
    if (id < 12288) accb[id] = 0.f;
    if (id < 3 * PADW * PADW) {
        int c = id / (PADW * PADW), rem = id % (PADW * PADW);
        int py = rem / PADW, px = rem % PADW;
        float v = 0.f;
        if (py >= 10 && py < 74 && px >= 10 && px < 74)
            v = image[((py - 10) * IMG + (px - 10)) * 3 + c];
        xp[id] = v;
    }
}

// fused max + normalize, single block
__global__ __launch_bounds__(1024) void k_maxnorm(const float* __restrict__ acc,
                                                  float* __restrict__ out) {
    int t = threadIdx.x;
    float m = -BIGF;
    for (int i = t; i < 12288; i += 1024) m = fmaxf(m, acc[i]);
    #pragma unroll
    for (int s = 1; s < 64; s <<= 1) m = fmaxf(m, __shfl_xor(m, s));
    __shared__ float ls[16];
    int lane = t & 63, w = t >> 6;
    if (lane == 0) ls[w] = m;
    __syncthreads();
    float mv = ls[0];
    #pragma unroll
    for (int i = 1; i < 16; ++i) mv = fmaxf(mv, ls[i]);
    for (int i = t; i < 12288; i += 1024) {
        int c = i >> 12, y = (i >> 6) & 63, x = i & 63;
        out[(y * IMG + x) * 3 + c] = acc[i] / mv;
    }
}

// ============================== fast path ===================================
// mem -> packed fp4 plane + exact f32 row sq-norms in one pass.
// Thread t owns 12 consecutive elems (3 float4, 48B aligned) -> 3 u16 stores.
// Nibble order: element e of each u16 at bits e*4 (identical pack for A & B).
__global__ __launch_bounds__(256) void k_quantmsq4(const float* __restrict__ mem,
                                                   u16* __restrict__ mq,
                                                   float* __restrict__ msq) {
    int j = blockIdx.x, t = threadIdx.x;
    const float4* r4 = (const float4*)(mem + (size_t)j * KDIM + t * 12);
    u16* dst = mq + (size_t)j * (ROWB / 2) + t * 3;
    float s = 0.f;
    #pragma unroll
    for (int g = 0; g < 3; ++g) {
        float4 v = r4[g];
        s += v.x * v.x + v.y * v.y + v.z * v.z + v.w * v.w;
        u32 pk = q4(v.x) | (q4(v.y) << 4) | (q4(v.z) << 8) | (q4(v.w) << 12);
        dst[g] = (u16)pk;
    }
    #pragma unroll
    for (int m = 1; m < 64; m <<= 1) s += __shfl_xor(s, m);
    __shared__ float ls[4];
    int lane = t & 63, w = t >> 6;
    if (lane == 0) ls[w] = s;
    __syncthreads();
    if (t == 0) msq[j] = ls[0] + ls[1] + ls[2] + ls[3];
}

// patch matrix (MPAD x KDIM) packed fp4, rows >= NP zero; 8 elems -> 1 u32
__global__ __launch_bounds__(256) void k_quantA4(const float* __restrict__ xp,
                                                 u32* __restrict__ aq) {
    int id = blockIdx.x * 256 + threadIdx.x;      // u32 units: MPAD*384
    int p = id / 384, k0 = (id - p * 384) * 8;
    u32 pk = 0;
    if (p < NP) {
        int c = k0 >> 10, kh = (k0 >> 5) & 31, kw = k0 & 31;
        int lh = p / LHW, lw = p - lh * LHW;
        const float* src = xp + c * (PADW * PADW) + (lh + kh) * PADW + lw + kw;
        #pragma unroll
        for (int e = 0; e < 8; ++e) pk |= q4(src[e]) << (e * 4);
    }
    aq[id] = pk;
}

// fp4 screening MFMA GEMM (scale=1.0); writes (D - 3072) as f16 + block mins.
// 128x128 tile, BK=256 fp4 (=128 B/row: SAME tile bytes, staging, swizzle and
// LDS layout as the r12/r14-VERIFIED i8 kernel), 4 waves of 64x64.
// r13 post-mortem fix: each lane's 16-byte fp4 fragment is DUPLICATED into
// both dword halves {d0..d3,d0..d3} of the v8i32 operand, eliminating the
// which-half ambiguity (correct whichever 4 dwords HW reads, for A and B
// independently). cbsz=blgp=4 (e2m1); e8m0 scale 0x7F = 2^0.
__global__ __launch_bounds__(256) void k_gemm_fp4(
    const char* __restrict__ Aq, const char* __restrict__ Bq,
    const float* __restrict__ msq, _Float16* __restrict__ Dm,
    float* __restrict__ pval)
{
    __shared__ __align__(16) char lds[65536];   // buf0/buf1: A @0, B @16384
    const int t = threadIdx.x;
    const int lane = t & 63;
    const int w = t >> 6, wm = w >> 1, wn = w & 1;
    const int mrow = lane & 15;

    // XCD-chunked bijective swizzle: 1408 = 8 * 176
    int L = blockIdx.x;
    int logical = (L & 7) * 176 + (L >> 3);
    int by = logical / 22, bx = logical - by * 22;
    const int rowBase = bx * 128;     // patch rows (A)
    const int jBase   = by * 128;     // mem rows (B)

    const int lrow = lane >> 3;             // 0..7
    const int gsrc = (lane & 7) ^ lrow;     // pre-swizzled 16B source group
    const char* gpl[8];
    unsigned ldsb[8];
    #pragma unroll
    for (int s = 0; s < 8; ++s) {
        int P = s >> 2, sub = s & 3;
        int row = sub * 32 + w * 8 + lrow;
        const char* basep = (P == 0 ? Aq : Bq);
        int gRow = (P == 0 ? rowBase : jBase) + row;
        gpl[s]  = basep + (size_t)gRow * ROWB + gsrc * 16;
        ldsb[s] = P * 16384 + (unsigned)(sub * 32 + w * 8) * 128;  // +lane*16 by HW
    }

    f32x4 acc[4][4];
    #pragma unroll
    for (int i = 0; i < 4; ++i)
        #pragma unroll
        for (int j = 0; j < 4; ++j) { f32x4 z = {0.f, 0.f, 0.f, 0.f}; acc[i][j] = z; }

    #pragma unroll
    for (int s = 0; s < 8; ++s)
        __builtin_amdgcn_global_load_lds(
            (const __attribute__((address_space(1))) void*)(gpl[s]),
            (__attribute__((address_space(3))) void*)(lds + ldsb[s]),
            16, 0, 0);

    for (int kc = 0; kc < 12; ++kc) {
        const int cb = kc & 1;
        __syncthreads();                       // vmcnt drain: buf[cb] ready
        if (kc < 11) {
            const unsigned nb = (cb ^ 1) * 32768u;
            #pragma unroll
            for (int s = 0; s < 8; ++s)
                __builtin_amdgcn_global_load_lds(
                    (const __attribute__((address_space(1))) void*)(gpl[s] + (kc + 1) * 128),
                    (__attribute__((address_space(3))) void*)(lds + nb + ldsb[s]),
                    16, 0, 0);
        }
        const char* lbase = lds + cb * 32768;
        #pragma unroll
        for (int kh2 = 0; kh2 < 2; ++kh2) {
            const int grp = kh2 * 4 + (lane >> 4);
            i32x8 ah[4];
            #pragma unroll
            for (int f = 0; f < 4; ++f) {
                int ra = wm * 64 + f * 16 + mrow;
                i32x4 d = *(const i32x4*)(lbase + ra * 128 + (grp ^ (ra & 7)) * 16);
                i32x8 a8 = {d[0], d[1], d[2], d[3], d[0], d[1], d[2], d[3]};
                ah[f] = a8;
            }
            #pragma unroll
            for (int fj = 0; fj < 4; ++fj) {
                int rb = wn * 64 + fj * 16 + mrow;
                i32x4 db = *(const i32x4*)(lbase + 16384 + rb * 128 + (grp ^ (rb & 7)) * 16);
                i32x8 bh = {db[0], db[1], db[2], db[3], db[0], db[1], db[2], db[3]};
                #pragma unroll
                for (int fi = 0; fi < 4; ++fi)
                    acc[fi][fj] = __builtin_amdgcn_mfma_scale_f32_16x16x128_f8f6f4(
                        ah[fi], bh, acc[fi][fj], 4, 4,
                        0, 0x7F7F7F7F, 0, 0x7F7F7F7F);
            }
        }
    }

    // epilogue: D = msq[j]-3072 - 2*score -> f16 store + 64-col block min
    float ms[4];
    #pragma unroll
    for (int fj = 0; fj < 4; ++fj) ms[fj] = msq[jBase + wn * 64 + fj * 16 + mrow] - 3072.0f;
    const int splitId = by * 2 + wn;
    #pragma unroll
    for (int fi = 0; fi < 4; ++fi) {
        #pragma unroll
        for (int r = 0; r < 4; ++r) {
            int p = rowBase + wm * 64 + fi * 16 + (lane >> 4) * 4 + r;
            float bv = BIGF;
            #pragma unroll
            for (int fj = 0; fj < 4; ++fj) {
                int j = jBase + wn * 64 + fj * 16 + mrow;
                float d = fmaf(-2.0f, acc[fi][fj][r], ms[fj]);
                Dm[(size_t)p * NMEM + j] = (_Float16)d;
                bv = fminf(bv, d);
            }
            #pragma unroll
            for (int m = 1; m < 16; m <<= 1) bv = fminf(bv, __shfl_xor(bv, m));
            if (mrow == 0 && p < NP)
                pval[(size_t)p * 128 + splitId] = bv;
        }
    }
}

// per-patch: in-block threshold from 128 block-mins, single Dm scan for
// candidates, exact f32 re-eval (r12/r14-verified logic unchanged)
__global__ __launch_bounds__(256) void k_refine(
    const _Float16* __restrict__ Dm, const float* __restrict__ pval,
    const float* __restrict__ msq, const float* __restrict__ xp,
    const float* __restrict__ mem, const int* __restrict__ mapping,
    int* __restrict__ rowIdx)
{
    const int p = blockIdx.x, t = threadIdx.x;
    const _Float16* row = Dm + (size_t)p * NMEM;
    const int lane = t & 63, w = t >> 6;

    __shared__ float wred[4];
    __shared__ int lcnt;
    __shared__ int list[256];
    __shared__ float thr_s;

    float pm = (t < 128) ? pval[(size_t)p * 128 + t] : BIGF;
    #pragma unroll
    for (int m = 1; m < 64; m <<= 1) pm = fminf(pm, __shfl_xor(pm, m));
    if (lane == 0) wred[w] = pm;
    if (t == 0) lcnt = 0;
    __syncthreads();
    if (t == 0)
        thr_s = fminf(fminf(wred[0], wred[1]), fminf(wred[2], wred[3]))
                + (MARGIN + 2.0f);   // +2 guards Dm's f16 rounding
    __syncthreads();
    const float th = thr_s;

    #pragma unroll
    for (int i0 = 0; i0 < 4; ++i0) {
        int base = i0 * 2048 + t * 8;
        f16x8 v = *(const f16x8*)(row + base);
        #pragma unroll
        for (int e = 0; e < 8; ++e)
            if ((float)v[e] <= th) {
                int sl = atomicAdd(&lcnt, 1);
                if (sl < 256) list[sl] = base + e;
            }
    }
    __syncthreads();
    int nc = min(lcnt, 256);

    const int lh = p / LHW, lw = p - (p / LHW) * LHW;
    float bd = BIGF; int bj = 0x7fffffff;
    __shared__ float tot;
    for (int ci = 0; ci < nc; ++ci) {
        int j = list[ci];
        const float* mrow2 = mem + (size_t)j * KDIM;
        float s = 0.f;
        for (int k = t; k < KDIM; k += 256) {
            int c = k >> 10, kh = (k >> 5) & 31, kw = k & 31;
            s += xp[c * (PADW * PADW) + (lh + kh) * PADW + lw + kw] * mrow2[k];
        }
        #pragma unroll
        for (int m = 1; m < 64; m <<= 1) s += __shfl_xor(s, m);
        if (lane == 0) wred[w] = s;
        __syncthreads();
        if (t == 0) tot = wred[0] + wred[1] + wred[2] + wred[3];
        __syncthreads();
        float d = msq[j] - 2.f * tot;
        if (d < bd || (d == bd && j < bj)) { bd = d; bj = j; }
    }
    if (t == 0) rowIdx[p] = mapping[bj];
}

// -------------------- overlap-add: barrier-free register scatter -----------
// r14-VERIFIED. Block (lh, c, chunk of lw). Thread (kh, g) owns px = g+8u,
// accumulates s[u] in registers, predicated atomicAdd into cropped output.
#define LWCH 4
__global__ __launch_bounds__(256) void k_scatter(const float* __restrict__ mem2,
                                                 const int* __restrict__ rowIdx,
                                                 float* __restrict__ accb) {
    int b = blockIdx.x;
    int ch = b & (LWCH - 1);
    int lc = b >> 2;
    const int lh = lc / 3, c = lc % 3;
    const int lw0 = ch * 14, lw1 = min(53, lw0 + 14);
    __shared__ int r2s[53];
    const int t = threadIdx.x;
    if (t >= lw0 && t < lw1) r2s[t] = rowIdx[lh * LHW + t];
    __syncthreads();
    const int kh = t >> 3;          // 0..31
    const int g  = t & 7;           // px = g + 8u
    float s[11];
    #pragma unroll
    for (int u = 0; u < 11; ++u) s[u] = 0.f;
    for (int lw = lw0; lw < lw1; ++lw) {
        const float* rowp = mem2 + (size_t)r2s[lw] * KDIM + c * 1024 + kh * 32;
        #pragma unroll
        for (int u = 0; u < 11; ++u) {
            int kw = g + 8 * u - lw;
            if (kw >= 0 && kw < 32) s[u] += rowp[kw];
        }
    }
    const int y = lh + kh - 10;
    if (y >= 0 && y < 64) {
        #pragma unroll
        for (int u = 0; u < 11; ++u) {
            int x = g + 8 * u - 10;
            if (x >= 0 && x < 64 && s[u] != 0.f)
                atomicAdd(&accb[c * 4096 + y * 64 + x], s[u]);
        }
    }
}

// ======================= legacy f32 pipeline (fallback) =====================
__global__ __launch_bounds__(256) void k_msq(const float* __restrict__ mem,
                                             float* __restrict__ msq) {
    int j = blockIdx.x;
    const float* row = mem + (size_t)j * KDIM;
    float s = 0.f;
    for (int i = threadIdx.x; i < KDIM; i += 256) { float v = row[i]; s += v * v; }
    #pragma unroll
    for (int m = 1; m < 64; m <<= 1) s += __shfl_xor(s, m);
    __shared__ float ls[4];
    int lane = threadIdx.x & 63, w = threadIdx.x >> 6;
    if (lane == 0) ls[w] = s;
    __syncthreads();
    if (threadIdx.x == 0) msq[j] = ls[0] + ls[1] + ls[2] + ls[3];
}

__global__ void k_amin(const float* __restrict__ pval, const int* __restrict__ pidx,
                       const int* __restrict__ mapping, int* __restrict__ rowIdx,
                       int nspl) {
    int p = blockIdx.x * 256 + threadIdx.x;
    if (p < NP) {
        float bv = BIGF; int bi = 0x7fffffff;
        for (int ns = 0; ns < nspl; ++ns) {
            float v = pval[(size_t)p * nspl + ns];
            int ix = pidx[(size_t)p * nspl + ns];
            if (v < bv || (v == bv && ix < bi)) { bv = v; bi = ix; }
        }
        rowIdx[p] = mapping[bi];
    }
}

__global__ __launch_bounds__(256) void k_gather(const float* __restrict__ mem2,
                                                const int* __restrict__ rowIdx,
                                                float* __restrict__ acc) {
    int b = blockIdx.x;
    int c = b >> 12, y = (b >> 6) & 63, x = b & 63;
    int khmin = max(0, y - 42), khmax = min(31, y + 10);
    int kwmin = max(0, x - 42), kwmax = min(31, x + 10);
    int nh = khmax - khmin + 1, nw = kwmax - kwmin + 1;
    int total = nh * nw;
    float s = 0.f;
    for (int idx = threadIdx.x; idx < total; idx += 256) {
        int kh = khmin + idx / nw;
        int kw = kwmin + idx % nw;
        int lh = y + 10 - kh, lw = x + 10 - kw;
        int p = lh * LHW + lw;
        int r2 = rowIdx[p];
        s += mem2[(size_t)r2 * KDIM + c * 1024 + kh * 32 + kw];
    }
    #pragma unroll
    for (int m = 1; m < 64; m <<= 1) s += __shfl_xor(s, m);
    __shared__ float ls[4];
    int lane = threadIdx.x & 63, w = threadIdx.x >> 6;
    if (lane == 0) ls[w] = s;
    __syncthreads();
    if (threadIdx.x == 0) acc[b] = ls[0] + ls[1] + ls[2] + ls[3];
}

__global__ __launch_bounds__(256) void k_gemm_argmin(
    const float* __restrict__ xp, const float* __restrict__ mem,
    const float* __restrict__ msq, float* __restrict__ pval,
    int* __restrict__ pidx)
{
    __shared__ float At[64][33];
    __shared__ float Bt[64][33];
    const int t = threadIdx.x;
    const int tx = t & 15, ty = t >> 4;
    const int rowBase = blockIdx.x * 64;
    const int nBase = blockIdx.y * NRANGE;

    float best[4]; int bidx[4];
    #pragma unroll
    for (int i = 0; i < 4; ++i) { best[i] = BIGF; bidx[i] = 0x7fffffff; }

    for (int nt = 0; nt < NRANGE / 64; ++nt) {
        const int jBase = nBase + nt * 64;
        float acc[4][4];
        #pragma unroll
        for (int i = 0; i < 4; ++i)
            #pragma unroll
            for (int j = 0; j < 4; ++j) acc[i][j] = 0.f;

        for (int kc = 0; kc < KDIM / 32; ++kc) {
            const int c = kc >> 5, kh = kc & 31;
            const float* xpc = xp + c * (PADW * PADW) + kh * PADW;
            #pragma unroll
            for (int i = 0; i < 8; ++i) {
                int e = i * 256 + t;
                int r = e >> 5, kwi = e & 31;
                int p = rowBase + r;
                float v = 0.f;
                if (p < NP) {
                    int lh = p / LHW, lw = p - lh * LHW;
                    v = xpc[lh * PADW + lw + kwi];
                }
                At[r][kwi] = v;
            }
            const float* mb = mem + (size_t)jBase * KDIM + kc * 32;
            #pragma unroll
            for (int i = 0; i < 8; ++i) {
                int e = i * 256 + t;
                int r = e >> 5, kwi = e & 31;
                Bt[r][kwi] = mb[(size_t)r * KDIM + kwi];
            }
            __syncthreads();
            #pragma unroll
            for (int kk = 0; kk < 32; ++kk) {
                float a[4], b[4];
                #pragma unroll
                for (int i = 0; i < 4; ++i) a[i] = At[ty + 16 * i][kk];
                #pragma unroll
                for (int j = 0; j < 4; ++j) b[j] = Bt[tx + 16 * j][kk];
                #pragma unroll
                for (int i = 0; i < 4; ++i)
                    #pragma unroll
                    for (int j = 0; j < 4; ++j) acc[i][j] += a[i] * b[j];
            }
            __syncthreads();
        }
        #pragma unroll
        for (int j = 0; j < 4; ++j) {
            int col = jBase + tx + 16 * j;
            float msv = msq[col];
            #pragma unroll
            for (int i = 0; i < 4; ++i) {
                float d = msv - 2.f * acc[i][j];
                if (d < best[i] || (d == best[i] && col < bidx[i])) {
                    best[i] = d; bidx[i] = col;
                }
            }
        }
    }
    #pragma unroll
    for (int m = 1; m < 16; m <<= 1) {
        #pragma unroll
        for (int i = 0; i < 4; ++i) {
            float ov = __shfl_xor(best[i], m);
            int   oi = __shfl_xor(bidx[i], m);
            if (ov < best[i] || (ov == best[i] && oi < bidx[i])) {
                best[i] = ov; bidx[i] = oi;
            }
        }
    }
    if (tx == 0) {
        #pragma unroll
        for (int i = 0; i < 4; ++i) {
            int p = rowBase + ty + 16 * i;
            if (p < NP) {
                pval[p * NSPL + blockIdx.y] = best[i];
                pidx[p * NSPL + blockIdx.y] = bidx[i];
            }
        }
    }
}

__global__ __launch_bounds__(256) void k_max(const float* __restrict__ acc,
                                             float* __restrict__ maxv) {
    float m = -BIGF;
    for (int i = threadIdx.x; i < 12288; i += 256) m = fmaxf(m, acc[i]);
    #pragma unroll
    for (int s = 1; s < 64; s <<= 1) m = fmaxf(m, __shfl_xor(m, s));
    __shared__ float ls[4];
    int lane = threadIdx.x & 63, w = threadIdx.x >> 6;
    if (lane == 0) ls[w] = m;
    __syncthreads();
    if (threadIdx.x == 0)
        maxv[0] = fmaxf(fmaxf(ls[0], ls[1]), fmaxf(ls[2], ls[3]));
}

__global__ void k_norm(const float* __restrict__ acc, const float* __restrict__ maxv,
                       float* __restrict__ out) {
    int id = blockIdx.x * 256 + threadIdx.x;
    if (id < 12288) {
        int c = id >> 12, y = (id >> 6) & 63, x = id & 63;
        out[(y * IMG + x) * 3 + c] = acc[id] / maxv[0];
    }
}

// ------------------------------------------------------------------- launch
extern "C" void kernel_launch(void* const* d_in, const int* in_sizes, int n_in,
                              void* d_out, int out_size, void* d_ws, size_t ws_size,
                              hipStream_t stream) {
    const float* image   = (const float*)d_in[0];
    const float* mem     = (const float*)d_in[1];
    const float* mem2    = (const float*)d_in[2];
    const int*   mapping = (const int*)d_in[3];

    if (ws_size >= WS_NEED6) {
        // ---- fast path: fp4 screen (dup-half fix) + exact refine ----------
        char* wsB = (char*)d_ws;
        float*    xp   = (float*)(wsB + O_XP);
        float*    msq  = (float*)(wsB + O_MSQ);
        u16*      mQ4  = (u16*)(wsB + O_MQ4);
        u32*      aQ4  = (u32*)(wsB + O_AQ4);
        _Float16* Dm   = (_Float16*)(wsB + O_D);
        float*    pval = (float*)(wsB + O_PVAL);
        int*      rowI = (int*)(wsB + O_ROWI);
        float*    accb = (float*)(wsB + O_ACC);

        k_xp<<<dim3((3 * PADW * PADW + 255) / 256), 256, 0, stream>>>(image, xp, accb);
        k_quantmsq4<<<dim3(NMEM), 256, 0, stream>>>(mem, mQ4, msq);
        k_quantA4<<<dim3(MPAD * 384 / 256), 256, 0, stream>>>(xp, aQ4);
        k_gemm_fp4<<<dim3(1408), 256, 0, stream>>>((const char*)aQ4, (const char*)mQ4,
                                                   msq, Dm, pval);
        k_refine<<<dim3(NP), 256, 0, stream>>>(Dm, pval, msq, xp, mem, mapping, rowI);
        k_scatter<<<dim3(LHW * 3 * LWCH), 256, 0, stream>>>(mem2, rowI, accb);
        k_maxnorm<<<dim3(1), 1024, 0, stream>>>(accb, (float*)d_out);
    } else {
        // ---------------- fallback: verified f32 pipeline ----------------
        float* ws   = (float*)d_ws;
        float* xp   = ws + F_XP;
        float* msq  = ws + F_MSQ;
        float* pval = ws + F_PVAL;
        int*   pidx = (int*)(ws + F_PIDX);
        int*   rowI = (int*)(ws + F_ROW);
        float* acc  = ws + F_ACC;
        float* maxv = ws + F_MAX;

        k_xp<<<dim3((3 * PADW * PADW + 255) / 256), 256, 0, stream>>>(image, xp, acc);
        k_msq<<<dim3(NMEM), 256, 0, stream>>>(mem, msq);
        k_gemm_argmin<<<dim3((NP + 63) / 64, NSPL), 256, 0, stream>>>(xp, mem, msq, pval, pidx);
        k_amin<<<dim3((NP + 255) / 256), 256, 0, stream>>>(pval, pidx, mapping, rowI, NSPL);
        k_gather<<<dim3(3 * IMG * IMG), 256, 0, stream>>>(mem2, rowI, acc);
        k_max<<<dim3(1), 256, 0, stream>>>(acc, maxv);
        k_norm<<<dim3((12288 + 255) / 256), 256, 0, stream>>>(acc, maxv, (float*)d_out);
    }
}

// Round 16
// 362.896 us; speedup vs baseline: 2.0912x; 2.0912x over previous
//
#include <hip/hip_runtime.h>

typedef unsigned short u16;
typedef unsigned int   u32;
typedef int      i32x4  __attribute__((ext_vector_type(4)));
typedef int      i32x8  __attribute__((ext_vector_type(8)));
typedef float    f32x4  __attribute__((ext_vector_type(4)));
typedef _Float16 f16x8  __attribute__((ext_vector_type(8)));

// Problem constants
#define LHW   53
#define NP    2809
#define KDIM  3072
#define NMEM  8192
#define PADW  84
#define IMG   64
#define MPAD  2816           // 22 * 128 zero-padded patch rows
#define BIGF  3.402823466e+38f
#define MARGIN 128.0f        // fp4-screen margin (~4-6 sigma incl. selection bias)
#define ROWB  1536           // bytes per fp4 row (3072 * 0.5)

// ---------------- fast-path ws layout (byte offsets, 256-aligned) ----------
#define O_XP    0UL           // 21168 f32
#define O_MSQ   84736UL       // 8192 f32
#define O_MQ4   117504UL      // 8192*1536 B fp4
#define O_AQ4   12700416UL    // 2816*1536 B fp4
#define O_D     17025792UL    // 2816*8192 f16 (D - 3072)
#define O_PVAL  63163136UL    // 2816*128 f32 block-mins
#define O_ROWI  64604928UL    // NP i32
#define O_ACC   64616192UL    // 12288 f32
#define WS_NEED6 64665344UL

// ---------------- legacy (fallback) ws layout (float-unit offsets) ---------
#define F_XP    0
#define F_MSQ   21504
#define F_PVAL  29696
#define F_PIDX  119584
#define F_ROW   209472
#define F_ACC   212288
#define F_MAX   224576
#define NSPL    32
#define NRANGE  (NMEM / NSPL)

// f32 -> OCP e2m1 nibble (s|e|e|m), RNE onto {0,.5,1,1.5,2,3,4,6}, clamp 6
__device__ inline u32 q4(float x) {
    float a = fminf(fabsf(x), 6.0f);
    u32 s = (__float_as_uint(x) >> 31) << 3;
    int v2;                                   // quantized value * 2
    if (a < 2.0f)      v2 = __float2int_rn(a * 2.0f);     // {0..4}
    else if (a < 4.0f) v2 = __float2int_rn(a) * 2;        // {4,6,8}
    else               v2 = __float2int_rn(a * 0.5f) * 4; // {8,12}
    u32 e;
    if (v2 <= 3)      e = (u32)v2;   // 0, 0.5, 1, 1.5
    else if (v2 == 4) e = 4u;        // 2
    else if (v2 == 6) e = 5u;        // 3
    else if (v2 == 8) e = 6u;        // 4
    else              e = 7u;        // 6
    return s | e;
}

// ============================ shared small kernels ==========================
// padded image; also zero-inits the output accumulator (atomic target)
__global__ void k_xp(const float* __restrict__ image, float* __restrict__ xp,
                     float* __restrict__ accb) {
    int id = blockIdx.x * 256 + threadIdx.x;
    if (id < 12288) accb[id] = 0.f;
    if (id < 3 * PADW * PADW) {
        int c = id / (PADW * PADW), rem = id % (PADW * PADW);
        int py = rem / PADW, px = rem % PADW;
        float v = 0.f;
        if (py >= 10 && py < 74 && px >= 10 && px < 74)
            v = image[((py - 10) * IMG + (px - 10)) * 3 + c];
        xp[id] = v;
    }
}

// fused max + normalize, single block
__global__ __launch_bounds__(1024) void k_maxnorm(const float* __restrict__ acc,
                                                  float* __restrict__ out) {
    int t = threadIdx.x;
    float m = -BIGF;
    for (int i = t; i < 12288; i += 1024) m = fmaxf(m, acc[i]);
    #pragma unroll
    for (int s = 1; s < 64; s <<= 1) m = fmaxf(m, __shfl_xor(m, s));
    __shared__ float ls[16];
    int lane = t & 63, w = t >> 6;
    if (lane == 0) ls[w] = m;
    __syncthreads();
    float mv = ls[0];
    #pragma unroll
    for (int i = 1; i < 16; ++i) mv = fmaxf(mv, ls[i]);
    for (int i = t; i < 12288; i += 1024) {
        int c = i >> 12, y = (i >> 6) & 63, x = i & 63;
        out[(y * IMG + x) * 3 + c] = acc[i] / mv;
    }
}

// ============================== fast path ===================================
// mem -> packed fp4 plane + exact f32 row sq-norms in one pass.
__global__ __launch_bounds__(256) void k_quantmsq4(const float* __restrict__ mem,
                                                   u16* __restrict__ mq,
                                                   float* __restrict__ msq) {
    int j = blockIdx.x, t = threadIdx.x;
    const float4* r4 = (const float4*)(mem + (size_t)j * KDIM + t * 12);
    u16* dst = mq + (size_t)j * (ROWB / 2) + t * 3;
    float s = 0.f;
    #pragma unroll
    for (int g = 0; g < 3; ++g) {
        float4 v = r4[g];
        s += v.x * v.x + v.y * v.y + v.z * v.z + v.w * v.w;
        u32 pk = q4(v.x) | (q4(v.y) << 4) | (q4(v.z) << 8) | (q4(v.w) << 12);
        dst[g] = (u16)pk;
    }
    #pragma unroll
    for (int m = 1; m < 64; m <<= 1) s += __shfl_xor(s, m);
    __shared__ float ls[4];
    int lane = t & 63, w = t >> 6;
    if (lane == 0) ls[w] = s;
    __syncthreads();
    if (t == 0) msq[j] = ls[0] + ls[1] + ls[2] + ls[3];
}

// patch matrix (MPAD x KDIM) packed fp4, rows >= NP zero; 8 elems -> 1 u32
__global__ __launch_bounds__(256) void k_quantA4(const float* __restrict__ xp,
                                                 u32* __restrict__ aq) {
    int id = blockIdx.x * 256 + threadIdx.x;      // u32 units: MPAD*384
    int p = id / 384, k0 = (id - p * 384) * 8;
    u32 pk = 0;
    if (p < NP) {
        int c = k0 >> 10, kh = (k0 >> 5) & 31, kw = k0 & 31;
        int lh = p / LHW, lw = p - lh * LHW;
        const float* src = xp + c * (PADW * PADW) + (lh + kh) * PADW + lw + kw;
        #pragma unroll
        for (int e = 0; e < 8; ++e) pk |= q4(src[e]) << (e * 4);
    }
    aq[id] = pk;
}

// fp4 screening MFMA GEMM (scale=1.0); writes (D - 3072) as f16 + block mins.
// r15-VERIFIED (passed, absmax 9.77e-4). Dup-half operand fix; cbsz=blgp=4.
__global__ __launch_bounds__(256) void k_gemm_fp4(
    const char* __restrict__ Aq, const char* __restrict__ Bq,
    const float* __restrict__ msq, _Float16* __restrict__ Dm,
    float* __restrict__ pval)
{
    __shared__ __align__(16) char lds[65536];   // buf0/buf1: A @0, B @16384
    const int t = threadIdx.x;
    const int lane = t & 63;
    const int w = t >> 6, wm = w >> 1, wn = w & 1;
    const int mrow = lane & 15;

    // XCD-chunked bijective swizzle: 1408 = 8 * 176
    int L = blockIdx.x;
    int logical = (L & 7) * 176 + (L >> 3);
    int by = logical / 22, bx = logical - by * 22;
    const int rowBase = bx * 128;     // patch rows (A)
    const int jBase   = by * 128;     // mem rows (B)

    const int lrow = lane >> 3;             // 0..7
    const int gsrc = (lane & 7) ^ lrow;     // pre-swizzled 16B source group
    const char* gpl[8];
    unsigned ldsb[8];
    #pragma unroll
    for (int s = 0; s < 8; ++s) {
        int P = s >> 2, sub = s & 3;
        int row = sub * 32 + w * 8 + lrow;
        const char* basep = (P == 0 ? Aq : Bq);
        int gRow = (P == 0 ? rowBase : jBase) + row;
        gpl[s]  = basep + (size_t)gRow * ROWB + gsrc * 16;
        ldsb[s] = P * 16384 + (unsigned)(sub * 32 + w * 8) * 128;  // +lane*16 by HW
    }

    f32x4 acc[4][4];
    #pragma unroll
    for (int i = 0; i < 4; ++i)
        #pragma unroll
        for (int j = 0; j < 4; ++j) { f32x4 z = {0.f, 0.f, 0.f, 0.f}; acc[i][j] = z; }

    #pragma unroll
    for (int s = 0; s < 8; ++s)
        __builtin_amdgcn_global_load_lds(
            (const __attribute__((address_space(1))) void*)(gpl[s]),
            (__attribute__((address_space(3))) void*)(lds + ldsb[s]),
            16, 0, 0);

    for (int kc = 0; kc < 12; ++kc) {
        const int cb = kc & 1;
        __syncthreads();                       // vmcnt drain: buf[cb] ready
        if (kc < 11) {
            const unsigned nb = (cb ^ 1) * 32768u;
            #pragma unroll
            for (int s = 0; s < 8; ++s)
                __builtin_amdgcn_global_load_lds(
                    (const __attribute__((address_space(1))) void*)(gpl[s] + (kc + 1) * 128),
                    (__attribute__((address_space(3))) void*)(lds + nb + ldsb[s]),
                    16, 0, 0);
        }
        const char* lbase = lds + cb * 32768;
        #pragma unroll
        for (int kh2 = 0; kh2 < 2; ++kh2) {
            const int grp = kh2 * 4 + (lane >> 4);
            i32x8 ah[4];
            #pragma unroll
            for (int f = 0; f < 4; ++f) {
                int ra = wm * 64 + f * 16 + mrow;
                i32x4 d = *(const i32x4*)(lbase + ra * 128 + (grp ^ (ra & 7)) * 16);
                i32x8 a8 = {d[0], d[1], d[2], d[3], d[0], d[1], d[2], d[3]};
                ah[f] = a8;
            }
            #pragma unroll
            for (int fj = 0; fj < 4; ++fj) {
                int rb = wn * 64 + fj * 16 + mrow;
                i32x4 db = *(const i32x4*)(lbase + 16384 + rb * 128 + (grp ^ (rb & 7)) * 16);
                i32x8 bh = {db[0], db[1], db[2], db[3], db[0], db[1], db[2], db[3]};
                #pragma unroll
                for (int fi = 0; fi < 4; ++fi)
                    acc[fi][fj] = __builtin_amdgcn_mfma_scale_f32_16x16x128_f8f6f4(
                        ah[fi], bh, acc[fi][fj], 4, 4,
                        0, 0x7F7F7F7F, 0, 0x7F7F7F7F);
            }
        }
    }

    // epilogue: D = msq[j]-3072 - 2*score -> f16 store + 64-col block min
    float ms[4];
    #pragma unroll
    for (int fj = 0; fj < 4; ++fj) ms[fj] = msq[jBase + wn * 64 + fj * 16 + mrow] - 3072.0f;
    const int splitId = by * 2 + wn;
    #pragma unroll
    for (int fi = 0; fi < 4; ++fi) {
        #pragma unroll
        for (int r = 0; r < 4; ++r) {
            int p = rowBase + wm * 64 + fi * 16 + (lane >> 4) * 4 + r;
            float bv = BIGF;
            #pragma unroll
            for (int fj = 0; fj < 4; ++fj) {
                int j = jBase + wn * 64 + fj * 16 + mrow;
                float d = fmaf(-2.0f, acc[fi][fj][r], ms[fj]);
                Dm[(size_t)p * NMEM + j] = (_Float16)d;
                bv = fminf(bv, d);
            }
            #pragma unroll
            for (int m = 1; m < 16; m <<= 1) bv = fminf(bv, __shfl_xor(bv, m));
            if (mrow == 0 && p < NP)
                pval[(size_t)p * 128 + splitId] = bv;
        }
    }
}

// per-patch refine, THROUGHPUT REWRITE (r15 post-mortem: old version was
// latency-serialized at ~6 us/candidate -> 620 us with fp4's ~9 cands/patch).
// 1. patch vector staged to LDS once (kills per-candidate xp gather)
// 2. candidates parallel across the 4 waves, no per-candidate barriers
// 3. mem rows read as coalesced float4; wave shfl-reduce; lexicographic
//    (d, j) combine across waves preserves exact first-index argmin.
__global__ __launch_bounds__(256) void k_refine(
    const _Float16* __restrict__ Dm, const float* __restrict__ pval,
    const float* __restrict__ msq, const float* __restrict__ xp,
    const float* __restrict__ mem, const int* __restrict__ mapping,
    int* __restrict__ rowIdx)
{
    const int p = blockIdx.x, t = threadIdx.x;
    const _Float16* row = Dm + (size_t)p * NMEM;
    const int lane = t & 63, w = t >> 6;

    __shared__ float xps[3072];
    __shared__ float wred[4];
    __shared__ float wbd[4];
    __shared__ int   wbj[4];
    __shared__ int lcnt;
    __shared__ int list[256];
    __shared__ float thr_s;

    // stage patch vector into LDS (gather once)
    const int lh = p / LHW, lw = p - lh * LHW;
    for (int i = t; i < 3072; i += 256) {
        int c = i >> 10, kh = (i >> 5) & 31, kw = i & 31;
        xps[i] = xp[c * (PADW * PADW) + (lh + kh) * PADW + lw + kw];
    }

    // threshold from the 128 split-mins
    float pm = (t < 128) ? pval[(size_t)p * 128 + t] : BIGF;
    #pragma unroll
    for (int m = 1; m < 64; m <<= 1) pm = fminf(pm, __shfl_xor(pm, m));
    if (lane == 0) wred[w] = pm;
    if (t == 0) lcnt = 0;
    __syncthreads();
    if (t == 0)
        thr_s = fminf(fminf(wred[0], wred[1]), fminf(wred[2], wred[3]))
                + (MARGIN + 2.0f);   // +2 guards Dm's f16 rounding
    __syncthreads();
    const float th = thr_s;

    // candidate scan (single pass over the f16 D row)
    #pragma unroll
    for (int i0 = 0; i0 < 4; ++i0) {
        int base = i0 * 2048 + t * 8;
        f16x8 v = *(const f16x8*)(row + base);
        #pragma unroll
        for (int e = 0; e < 8; ++e)
            if ((float)v[e] <= th) {
                int sl = atomicAdd(&lcnt, 1);
                if (sl < 256) list[sl] = base + e;
            }
    }
    __syncthreads();
    int nc = min(lcnt, 256);

    // parallel-wave exact f32 evaluation
    float bd = BIGF; int bj = 0x7fffffff;
    for (int ci = w; ci < nc; ci += 4) {
        int j = list[ci];
        const float4* mr = (const float4*)(mem + (size_t)j * KDIM);
        float s = 0.f;
        #pragma unroll
        for (int it = 0; it < 12; ++it) {
            int idx = it * 64 + lane;          // float4 index 0..767
            float4 mv = mr[idx];
            const float* xv = &xps[idx * 4];
            s += mv.x * xv[0] + mv.y * xv[1] + mv.z * xv[2] + mv.w * xv[3];
        }
        #pragma unroll
        for (int m = 1; m < 64; m <<= 1) s += __shfl_xor(s, m);
        float d = msq[j] - 2.f * s;
        if (d < bd || (d == bd && j < bj)) { bd = d; bj = j; }
    }
    if (lane == 0) { wbd[w] = bd; wbj[w] = bj; }
    __syncthreads();
    if (t == 0) {
        float Bd = wbd[0]; int Bj = wbj[0];
        #pragma unroll
        for (int i = 1; i < 4; ++i)
            if (wbd[i] < Bd || (wbd[i] == Bd && wbj[i] < Bj)) { Bd = wbd[i]; Bj = wbj[i]; }
        if (Bj == 0x7fffffff) Bj = 0;   // unreachable guard
        rowIdx[p] = mapping[Bj];
    }
}

// -------------------- overlap-add: barrier-free register scatter -----------
// r14-VERIFIED. Block (lh, c, chunk of lw). Thread (kh, g) owns px = g+8u,
// accumulates s[u] in registers, predicated atomicAdd into cropped output.
#define LWCH 4
__global__ __launch_bounds__(256) void k_scatter(const float* __restrict__ mem2,
                                                 const int* __restrict__ rowIdx,
                                                 float* __restrict__ accb) {
    int b = blockIdx.x;
    int ch = b & (LWCH - 1);
    int lc = b >> 2;
    const int lh = lc / 3, c = lc % 3;
    const int lw0 = ch * 14, lw1 = min(53, lw0 + 14);
    __shared__ int r2s[53];
    const int t = threadIdx.x;
    if (t >= lw0 && t < lw1) r2s[t] = rowIdx[lh * LHW + t];
    __syncthreads();
    const int kh = t >> 3;          // 0..31
    const int g  = t & 7;           // px = g + 8u
    float s[11];
    #pragma unroll
    for (int u = 0; u < 11; ++u) s[u] = 0.f;
    for (int lw = lw0; lw < lw1; ++lw) {
        const float* rowp = mem2 + (size_t)r2s[lw] * KDIM + c * 1024 + kh * 32;
        #pragma unroll
        for (int u = 0; u < 11; ++u) {
            int kw = g + 8 * u - lw;
            if (kw >= 0 && kw < 32) s[u] += rowp[kw];
        }
    }
    const int y = lh + kh - 10;
    if (y >= 0 && y < 64) {
        #pragma unroll
        for (int u = 0; u < 11; ++u) {
            int x = g + 8 * u - 10;
            if (x >= 0 && x < 64 && s[u] != 0.f)
                atomicAdd(&accb[c * 4096 + y * 64 + x], s[u]);
        }
    }
}

// ======================= legacy f32 pipeline (fallback) =====================
__global__ __launch_bounds__(256) void k_msq(const float* __restrict__ mem,
                                             float* __restrict__ msq) {
    int j = blockIdx.x;
    const float* row = mem + (size_t)j * KDIM;
    float s = 0.f;
    for (int i = threadIdx.x; i < KDIM; i += 256) { float v = row[i]; s += v * v; }
    #pragma unroll
    for (int m = 1; m < 64; m <<= 1) s += __shfl_xor(s, m);
    __shared__ float ls[4];
    int lane = threadIdx.x & 63, w = threadIdx.x >> 6;
    if (lane == 0) ls[w] = s;
    __syncthreads();
    if (threadIdx.x == 0) msq[j] = ls[0] + ls[1] + ls[2] + ls[3];
}

__global__ void k_amin(const float* __restrict__ pval, const int* __restrict__ pidx,
                       const int* __restrict__ mapping, int* __restrict__ rowIdx,
                       int nspl) {
    int p = blockIdx.x * 256 + threadIdx.x;
    if (p < NP) {
        float bv = BIGF; int bi = 0x7fffffff;
        for (int ns = 0; ns < nspl; ++ns) {
            float v = pval[(size_t)p * nspl + ns];
            int ix = pidx[(size_t)p * nspl + ns];
            if (v < bv || (v == bv && ix < bi)) { bv = v; bi = ix; }
        }
        rowIdx[p] = mapping[bi];
    }
}

__global__ __launch_bounds__(256) void k_gather(const float* __restrict__ mem2,
                                                const int* __restrict__ rowIdx,
                                                float* __restrict__ acc) {
    int b = blockIdx.x;
    int c = b >> 12, y = (b >> 6) & 63, x = b & 63;
    int khmin = max(0, y - 42), khmax = min(31, y + 10);
    int kwmin = max(0, x - 42), kwmax = min(31, x + 10);
    int nh = khmax - khmin + 1, nw = kwmax - kwmin + 1;
    int total = nh * nw;
    float s = 0.f;
    for (int idx = threadIdx.x; idx < total; idx += 256) {
        int kh = khmin + idx / nw;
        int kw = kwmin + idx % nw;
        int lh = y + 10 - kh, lw = x + 10 - kw;
        int p = lh * LHW + lw;
        int r2 = rowIdx[p];
        s += mem2[(size_t)r2 * KDIM + c * 1024 + kh * 32 + kw];
    }
    #pragma unroll
    for (int m = 1; m < 64; m <<= 1) s += __shfl_xor(s, m);
    __shared__ float ls[4];
    int lane = threadIdx.x & 63, w = threadIdx.x >> 6;
    if (lane == 0) ls[w] = s;
    __syncthreads();
    if (threadIdx.x == 0) acc[b] = ls[0] + ls[1] + ls[2] + ls[3];
}

__global__ __launch_bounds__(256) void k_gemm_argmin(
    const float* __restrict__ xp, const float* __restrict__ mem,
    const float* __restrict__ msq, float* __restrict__ pval,
    int* __restrict__ pidx)
{
    __shared__ float At[64][33];
    __shared__ float Bt[64][33];
    const int t = threadIdx.x;
    const int tx = t & 15, ty = t >> 4;
    const int rowBase = blockIdx.x * 64;
    const int nBase = blockIdx.y * NRANGE;

    float best[4]; int bidx[4];
    #pragma unroll
    for (int i = 0; i < 4; ++i) { best[i] = BIGF; bidx[i] = 0x7fffffff; }

    for (int nt = 0; nt < NRANGE / 64; ++nt) {
        const int jBase = nBase + nt * 64;
        float acc[4][4];
        #pragma unroll
        for (int i = 0; i < 4; ++i)
            #pragma unroll
            for (int j = 0; j < 4; ++j) acc[i][j] = 0.f;

        for (int kc = 0; kc < KDIM / 32; ++kc) {
            const int c = kc >> 5, kh = kc & 31;
            const float* xpc = xp + c * (PADW * PADW) + kh * PADW;
            #pragma unroll
            for (int i = 0; i < 8; ++i) {
                int e = i * 256 + t;
                int r = e >> 5, kwi = e & 31;
                int p = rowBase + r;
                float v = 0.f;
                if (p < NP) {
                    int lh = p / LHW, lw = p - lh * LHW;
                    v = xpc[lh * PADW + lw + kwi];
                }
                At[r][kwi] = v;
            }
            const float* mb = mem + (size_t)jBase * KDIM + kc * 32;
            #pragma unroll
            for (int i = 0; i < 8; ++i) {
                int e = i * 256 + t;
                int r = e >> 5, kwi = e & 31;
                Bt[r][kwi] = mb[(size_t)r * KDIM + kwi];
            }
            __syncthreads();
            #pragma unroll
            for (int kk = 0; kk < 32; ++kk) {
                float a[4], b[4];
                #pragma unroll
                for (int i = 0; i < 4; ++i) a[i] = At[ty + 16 * i][kk];
                #pragma unroll
                for (int j = 0; j < 4; ++j) b[j] = Bt[tx + 16 * j][kk];
                #pragma unroll
                for (int i = 0; i < 4; ++i)
                    #pragma unroll
                    for (int j = 0; j < 4; ++j) acc[i][j] += a[i] * b[j];
            }
            __syncthreads();
        }
        #pragma unroll
        for (int j = 0; j < 4; ++j) {
            int col = jBase + tx + 16 * j;
            float msv = msq[col];
            #pragma unroll
            for (int i = 0; i < 4; ++i) {
                float d = msv - 2.f * acc[i][j];
                if (d < best[i] || (d == best[i] && col < bidx[i])) {
                    best[i] = d; bidx[i] = col;
                }
            }
        }
    }
    #pragma unroll
    for (int m = 1; m < 16; m <<= 1) {
        #pragma unroll
        for (int i = 0; i < 4; ++i) {
            float ov = __shfl_xor(best[i], m);
            int   oi = __shfl_xor(bidx[i], m);
            if (ov < best[i] || (ov == best[i] && oi < bidx[i])) {
                best[i] = ov; bidx[i] = oi;
            }
        }
    }
    if (tx == 0) {
        #pragma unroll
        for (int i = 0; i < 4; ++i) {
            int p = rowBase + ty + 16 * i;
            if (p < NP) {
                pval[p * NSPL + blockIdx.y] = best[i];
                pidx[p * NSPL + blockIdx.y] = bidx[i];
            }
        }
    }
}

__global__ __launch_bounds__(256) void k_max(const float* __restrict__ acc,
                                             float* __restrict__ maxv) {
    float m = -BIGF;
    for (int i = threadIdx.x; i < 12288; i += 256) m = fmaxf(m, acc[i]);
    #pragma unroll
    for (int s = 1; s < 64; s <<= 1) m = fmaxf(m, __shfl_xor(m, s));
    __shared__ float ls[4];
    int lane = threadIdx.x & 63, w = threadIdx.x >> 6;
    if (lane == 0) ls[w] = m;
    __syncthreads();
    if (threadIdx.x == 0)
        maxv[0] = fmaxf(fmaxf(ls[0], ls[1]), fmaxf(ls[2], ls[3]));
}

__global__ void k_norm(const float* __restrict__ acc, const float* __restrict__ maxv,
                       float* __restrict__ out) {
    int id = blockIdx.x * 256 + threadIdx.x;
    if (id < 12288) {
        int c = id >> 12, y = (id >> 6) & 63, x = id & 63;
        out[(y * IMG + x) * 3 + c] = acc[id] / maxv[0];
    }
}

// ------------------------------------------------------------------- launch
extern "C" void kernel_launch(void* const* d_in, const int* in_sizes, int n_in,
                              void* d_out, int out_size, void* d_ws, size_t ws_size,
                              hipStream_t stream) {
    const float* image   = (const float*)d_in[0];
    const float* mem     = (const float*)d_in[1];
    const float* mem2    = (const float*)d_in[2];
    const int*   mapping = (const int*)d_in[3];

    if (ws_size >= WS_NEED6) {
        // ---- fast path: fp4 screen + parallel-wave refine + reg scatter ---
        char* wsB = (char*)d_ws;
        float*    xp   = (float*)(wsB + O_XP);
        float*    msq  = (float*)(wsB + O_MSQ);
        u16*      mQ4  = (u16*)(wsB + O_MQ4);
        u32*      aQ4  = (u32*)(wsB + O_AQ4);
        _Float16* Dm   = (_Float16*)(wsB + O_D);
        float*    pval = (float*)(wsB + O_PVAL);
        int*      rowI = (int*)(wsB + O_ROWI);
        float*    accb = (float*)(wsB + O_ACC);

        k_xp<<<dim3((3 * PADW * PADW + 255) / 256), 256, 0, stream>>>(image, xp, accb);
        k_quantmsq4<<<dim3(NMEM), 256, 0, stream>>>(mem, mQ4, msq);
        k_quantA4<<<dim3(MPAD * 384 / 256), 256, 0, stream>>>(xp, aQ4);
        k_gemm_fp4<<<dim3(1408), 256, 0, stream>>>((const char*)aQ4, (const char*)mQ4,
                                                   msq, Dm, pval);
        k_refine<<<dim3(NP), 256, 0, stream>>>(Dm, pval, msq, xp, mem, mapping, rowI);
        k_scatter<<<dim3(LHW * 3 * LWCH), 256, 0, stream>>>(mem2, rowI, accb);
        k_maxnorm<<<dim3(1), 1024, 0, stream>>>(accb, (float*)d_out);
    } else {
        // ---------------- fallback: verified f32 pipeline ----------------
        float* ws   = (float*)d_ws;
        float* xp   = ws + F_XP;
        float* msq  = ws + F_MSQ;
        float* pval = ws + F_PVAL;
        int*   pidx = (int*)(ws + F_PIDX);
        int*   rowI = (int*)(ws + F_ROW);
        float* acc  = ws + F_ACC;
        float* maxv = ws + F_MAX;

        k_xp<<<dim3((3 * PADW * PADW + 255) / 256), 256, 0, stream>>>(image, xp, acc);
        k_msq<<<dim3(NMEM), 256, 0, stream>>>(mem, msq);
        k_gemm_argmin<<<dim3((NP + 63) / 64, NSPL), 256, 0, stream>>>(xp, mem, msq, pval, pidx);
        k_amin<<<dim3((NP + 255) / 256), 256, 0, stream>>>(pval, pidx, mapping, rowI, NSPL);
        k_gather<<<dim3(3 * IMG * IMG), 256, 0, stream>>>(mem2, rowI, acc);
        k_max<<<dim3(1), 256, 0, stream>>>(acc, maxv);
        k_norm<<<dim3((12288 + 255) / 256), 256, 0, stream>>>(acc, maxv, (float*)d_out);
    }
}